// Round 10
// baseline (47696.008 us; speedup 1.0000x reference)
//
#include <hip/hip_runtime.h>
#include <math.h>

// SimpleRNN B=64,T=512,V=96,H=1024. out=[logits fp32 32768*96][h_last fp32 64*1024]
//
// ROUND 10 = ROUND 9 resubmitted verbatim (round 9 hit GPUAcquisitionTimeout;
// the ground-truth baseline has never run). Zero cleverness, single code path:
//   - pure fp32 scalar VALU (no MFMA, no bf16, no limb splitting)
//   - no __device__ statics, no LDS games, no inter-block sync, no memset
//   - ws used ONLY for a 512 KB fp32 h double-buffer (round 8 proved ws >= 768 KB works)
//   - 512 step launches + 512 per-step logits launches, stream-ordered
// Purpose: establish a PASSING anchor; reintroduce MFMA layer-by-layer afterwards.
// Round-8 post-mortem: error 57.26 is unreachable from tanh-bounded h @ Wl (<=32),
// so some stacked mechanism (MFMA layout / limbs / plan select) is broken; this
// kernel removes all of them at once.

// ---- h0 -> parity-0 half of fp32 double buffer. grid 256x256 ----
__global__ void rnn_h0(const float* __restrict__ h0, float* __restrict__ hbuf) {
  int i = blockIdx.x * 256 + threadIdx.x;   // 0..65535
  hbuf[i] = h0[i];
}

// ---- one step: h_nxt[b][n] = tanh(bh[n] + x[b,t,:]@Wxh[:,n] + h_cur[b,:]@Whh[:,n])
// grid 256x256: b = bid>>2, n = (bid&3)*256 + tid. Whh reads coalesced across lanes;
// x row and h row are wave-broadcast. All fp32 fma, sequential k (matches numpy order).
__global__ void rnn_step_f(const float* __restrict__ x, const float* __restrict__ Wxh,
                           const float* __restrict__ Whh, const float* __restrict__ bh,
                           const float* __restrict__ hcur, float* __restrict__ hnxt,
                           float* __restrict__ hlast, int t) {
  const int b = blockIdx.x >> 2;
  const int n = (blockIdx.x & 3) * 256 + threadIdx.x;
  const float* xr = x + ((size_t)b * 512 + t) * 96;
  const float* hr = hcur + b * 1024;
  float s = bh[n];
  #pragma unroll 4
  for (int v = 0; v < 96; ++v) s = fmaf(xr[v], Wxh[(size_t)v * 1024 + n], s);
  #pragma unroll 4
  for (int k = 0; k < 1024; ++k) s = fmaf(hr[k], Whh[(size_t)k * 1024 + n], s);
  const float hv = tanhf(s);
  hnxt[b * 1024 + n] = hv;
  if (t == 511) hlast[b * 1024 + n] = hv;   // h_last output, fp32
}

// ---- per-step logits: out[(b*512+t)*96 + v] = bl[v] + h_nxt[b,:]@Wl[v,:]
// grid 24x256: idx = bid*256+tid in 0..6143; b = idx/96, v = idx%96.
__global__ void rnn_logits_f(const float* __restrict__ hnew, const float* __restrict__ Wl,
                             const float* __restrict__ bl, float* __restrict__ out, int t) {
  const int idx = blockIdx.x * 256 + threadIdx.x;   // 0..6143
  const int b = idx / 96, v = idx - b * 96;
  const float* hr = hnew + b * 1024;
  const float* wr = Wl + (size_t)v * 1024;
  float s = bl[v];
  #pragma unroll 4
  for (int k = 0; k < 1024; ++k) s = fmaf(hr[k], wr[k], s);
  out[((size_t)b * 512 + t) * 96 + v] = s;
}

// ---- launch: 1025 sequential launches, single code path ----
extern "C" void kernel_launch(void* const* d_in, const int* in_sizes, int n_in,
                              void* d_out, int out_size, void* d_ws, size_t ws_size,
                              hipStream_t stream) {
  const float* x   = (const float*)d_in[0];
  const float* h0  = (const float*)d_in[1];
  const float* Wxh = (const float*)d_in[2];
  const float* Whh = (const float*)d_in[3];
  const float* bh  = (const float*)d_in[4];
  const float* Wl  = (const float*)d_in[5];
  const float* bl  = (const float*)d_in[6];
  float* out   = (float*)d_out;
  float* hlast = out + (size_t)32768 * 96;
  (void)in_sizes; (void)n_in; (void)out_size;

  if (d_ws == nullptr || ws_size < 524288) return;  // need 2x64x1024 fp32 = 512 KB
  float* hb = (float*)d_ws;                         // [2][64][1024]

  rnn_h0<<<256, 256, 0, stream>>>(h0, hb);
  for (int t = 0; t < 512; ++t) {
    float* hcur = hb + (size_t)(t & 1) * 65536;
    float* hnxt = hb + (size_t)((t & 1) ^ 1) * 65536;
    rnn_step_f<<<256, 256, 0, stream>>>(x, Wxh, Whh, bh, hcur, hnxt, hlast, t);
    rnn_logits_f<<<24, 256, 0, stream>>>(hnxt, Wl, bl, out, t);
  }
}

// Round 11
// 21492.279 us; speedup vs baseline: 2.2192x; 2.2192x over previous
//
#include <hip/hip_runtime.h>
#include <math.h>

// SimpleRNN B=64,T=512,V=96,H=1024. out=[logits fp32 32768*96][h_last fp32 64*1024]
//
// ROUND 11: anchor (round 10, PASS 47.7ms) + ONE new mechanism: MFMA 3-limb step.
//  - launch-per-step retained, but fused: launch t runs step(t) blocks [0,256) and
//    logits(t-1) blocks [256,280) — logits reads the h parity written by launch t-1,
//    step reads the same parity and writes the other; no intra-launch dependency.
//  - ws = 768 KB exactly (proven round 8): 3-limb bf16 h double-buffer [2][64][1024].
//  - logits: scalar fp32 per (b,v) as in the anchor, + short8/float4 loads and 4
//    k-quarter accumulators (ILP); h = hi+mid limbs (error ~2^-17, fp32-class).
//  - step: 16x16x32 bf16 MFMA, 6 limb products (a1b1,a1b2,a2b1,a1b3,a2b2,a3b1);
//    Whh/Wxh limbs split in-kernel from fp32 (64KB/block slice, L2-hot).
// If this fails big: the MFMA-3-limb step path is definitively the broken mechanism.

typedef __attribute__((ext_vector_type(8))) short short8;   // 8 x bf16
typedef __attribute__((ext_vector_type(4))) float f32x4;

#define MFMA16 __builtin_amdgcn_mfma_f32_16x16x32_bf16

__device__ __forceinline__ unsigned short f2bf(float f) {
  union { float f; unsigned u; } v; v.f = f;
  unsigned r = v.u + 0x7fff + ((v.u >> 16) & 1);   // RNE
  return (unsigned short)(r >> 16);
}
__device__ __forceinline__ float bfhead(float f, unsigned short* bits) {
  union { float f; unsigned u; } v; v.f = f;
  unsigned r = (v.u + 0x7fff + ((v.u >> 16) & 1)) & 0xffff0000u;
  *bits = (unsigned short)(r >> 16);
  union { unsigned u; float f; } o; o.u = r; return o.f;
}
__device__ __forceinline__ void split3(float f, unsigned short& a, unsigned short& b,
                                       unsigned short& c) {
  float h1 = bfhead(f, &a);
  float r1 = f - h1;          // exact
  float h2 = bfhead(r1, &b);
  c = f2bf(r1 - h2);
}
__device__ __forceinline__ float bf2f(unsigned short u) {
  union { unsigned u; float f; } v; v.u = ((unsigned)u) << 16; return v.f;
}

// ---- h0 -> 3-limb double buffer, parity 0. grid 256x256 ----
__global__ void rnn_h0(const float* __restrict__ h0, unsigned short* __restrict__ hb1,
                       unsigned short* __restrict__ hb2, unsigned short* __restrict__ hb3) {
  int i = blockIdx.x * 256 + threadIdx.x;   // 0..65535
  unsigned short a, b, c; split3(h0[i], a, b, c);
  hb1[i] = a; hb2[i] = b; hb3[i] = c;
}

// ---- fused launch t (t=0..512), grid 280x256 ----
// blocks [0,256):  step t (skip t==512): h_{t+1} = tanh(x_t@Wxh + bh + h_t@Whh)
//                  reads limb parity t&1, writes parity (t+1)&1
// blocks [256,280): logits row t-1 (skip t==0): from limb parity t&1 (= h_t)
__global__ __launch_bounds__(256) void rnn_fused(
    const float* __restrict__ x, const float* __restrict__ Wxh,
    const float* __restrict__ Whh, const float* __restrict__ bh,
    const float* __restrict__ Wl, const float* __restrict__ bl,
    unsigned short* __restrict__ hb1, unsigned short* __restrict__ hb2,
    unsigned short* __restrict__ hb3,
    float* __restrict__ out, float* __restrict__ hlast, int t)
{
  const int tid = threadIdx.x;
  if (blockIdx.x >= 256) {            // ---------- logits role ----------
    if (t < 1) return;
    const int idx = (blockIdx.x - 256) * 256 + tid;   // 0..6143
    const int b = idx / 96, v = idx - b * 96;
    const int cur = (t & 1) * 65536;
    const unsigned short* h1 = hb1 + cur + b * 1024;
    const unsigned short* h2 = hb2 + cur + b * 1024;
    const float* wr = Wl + (size_t)v * 1024;
    float s[4] = {0.f, 0.f, 0.f, 0.f};
    for (int i = 0; i < 32; ++i) {
      #pragma unroll
      for (int q = 0; q < 4; ++q) {
        const int off = q * 256 + i * 8;
        short8 u1 = *(const short8*)(h1 + off);
        short8 u2 = *(const short8*)(h2 + off);
        f32x4 wa = *(const f32x4*)(wr + off);
        f32x4 wb = *(const f32x4*)(wr + off + 4);
        #pragma unroll
        for (int j = 0; j < 4; ++j)
          s[q] = fmaf(bf2f((unsigned short)u1[j]) + bf2f((unsigned short)u2[j]), wa[j], s[q]);
        #pragma unroll
        for (int j = 0; j < 4; ++j)
          s[q] = fmaf(bf2f((unsigned short)u1[4 + j]) + bf2f((unsigned short)u2[4 + j]), wb[j], s[q]);
      }
    }
    out[((size_t)b * 512 + (t - 1)) * 96 + v] = ((s[0] + s[1]) + (s[2] + s[3])) + bl[v];
    return;
  }

  // ---------- step role ----------
  if (t >= 512) return;
  const int lane = tid & 63, w = tid >> 6;
  const int bid = blockIdx.x, g = bid >> 6, b0 = g * 16, n0 = (bid & 63) * 16;
  const int lc = lane & 15, lk8 = (lane >> 4) * 8;
  const int kw0 = w * 256;
  const int cur = (t & 1) * 65536, nxt = ((t + 1) & 1) * 65536;

  f32x4 aA = {0,0,0,0}, aB = {0,0,0,0}, aC = {0,0,0,0};
  #pragma unroll
  for (int kt = 0; kt < 8; ++kt) {
    const int ko = kw0 + kt * 32 + lk8;
    const size_t ao = (size_t)cur + (size_t)(b0 + lc) * 1024 + ko;
    short8 a1 = *(const short8*)(hb1 + ao);
    short8 a2 = *(const short8*)(hb2 + ao);
    short8 a3 = *(const short8*)(hb3 + ao);
    short8 b1, b2, b3;
    #pragma unroll
    for (int j = 0; j < 8; ++j) {   // in-kernel 3-limb split of Whh[k][n] slice
      unsigned short ua, ub, uc;
      split3(Whh[(size_t)(ko + j) * 1024 + n0 + lc], ua, ub, uc);
      b1[j] = (short)ua; b2[j] = (short)ub; b3[j] = (short)uc;
    }
    aA = MFMA16(a1, b1, aA, 0, 0, 0);
    aB = MFMA16(a1, b2, aB, 0, 0, 0);
    aC = MFMA16(a2, b1, aC, 0, 0, 0);
    aB = MFMA16(a1, b3, aB, 0, 0, 0);
    aC = MFMA16(a2, b2, aC, 0, 0, 0);
    aA = MFMA16(a3, b1, aA, 0, 0, 0);
  }
  if (w >= 1) {          // fused x_t @ Wxh: waves 1..3 own the 3 k-tiles of K=96
    const int kb = (w - 1) * 32 + lk8;
    short8 xw1, xw2, xw3, x1, x2, x3;
    #pragma unroll
    for (int j = 0; j < 8; ++j) {
      unsigned short ua, ub, uc;
      split3(Wxh[(size_t)(kb + j) * 1024 + n0 + lc], ua, ub, uc);
      xw1[j] = (short)ua; xw2[j] = (short)ub; xw3[j] = (short)uc;
    }
    const float* xp = x + ((size_t)(b0 + lc) * 512 + t) * 96 + kb;
    #pragma unroll
    for (int j = 0; j < 8; ++j) {
      unsigned short ua, ub, uc; split3(xp[j], ua, ub, uc);
      x1[j] = (short)ua; x2[j] = (short)ub; x3[j] = (short)uc;
    }
    aA = MFMA16(x1, xw1, aA, 0, 0, 0);
    aB = MFMA16(x1, xw2, aB, 0, 0, 0);
    aC = MFMA16(x2, xw1, aC, 0, 0, 0);
    aB = MFMA16(x1, xw3, aB, 0, 0, 0);
    aC = MFMA16(x2, xw2, aC, 0, 0, 0);
    aA = MFMA16(x3, xw1, aA, 0, 0, 0);
  }

  __shared__ float part[4][16][17];
  #pragma unroll
  for (int r = 0; r < 4; ++r)
    part[w][(lane >> 4) * 4 + r][lc] = aA[r] + aB[r] + aC[r];
  __syncthreads();

  const int row = (lane >> 4) * 4 + w;    // bijective over 16 rows across 4 waves
  const int b = b0 + row;
  float s = part[0][row][lc] + part[1][row][lc]
          + part[2][row][lc] + part[3][row][lc] + bh[n0 + lc];
  const float hv = tanhf(s);
  unsigned short u1, u2, u3; split3(hv, u1, u2, u3);
  const size_t ho = (size_t)nxt + (size_t)b * 1024 + n0 + lc;
  hb1[ho] = u1; hb2[ho] = u2; hb3[ho] = u3;
  if (t == 511) hlast[(size_t)b * 1024 + n0 + lc] = hv;
}

// ---- launch: 1 init + 513 fused launches ----
extern "C" void kernel_launch(void* const* d_in, const int* in_sizes, int n_in,
                              void* d_out, int out_size, void* d_ws, size_t ws_size,
                              hipStream_t stream) {
  const float* x   = (const float*)d_in[0];
  const float* h0  = (const float*)d_in[1];
  const float* Wxh = (const float*)d_in[2];
  const float* Whh = (const float*)d_in[3];
  const float* bh  = (const float*)d_in[4];
  const float* Wl  = (const float*)d_in[5];
  const float* bl  = (const float*)d_in[6];
  float* out   = (float*)d_out;
  float* hlast = out + (size_t)32768 * 96;
  (void)in_sizes; (void)n_in; (void)out_size;

  if (d_ws == nullptr || ws_size < 786432) return;  // 3 x 256KB limb double-buffers
  unsigned short* hb1 = (unsigned short*)d_ws;            // [2][64][1024]
  unsigned short* hb2 = hb1 + 131072;
  unsigned short* hb3 = hb2 + 131072;

  rnn_h0<<<256, 256, 0, stream>>>(h0, hb1, hb2, hb3);
  for (int t = 0; t <= 512; ++t)
    rnn_fused<<<280, 256, 0, stream>>>(x, Wxh, Whh, bh, Wl, bl,
                                       hb1, hb2, hb3, out, hlast, t);
}